// Round 5
// baseline (482.159 us; speedup 1.0000x reference)
//
#include <hip/hip_runtime.h>
#include <hip/hip_bf16.h>
#include <cmath>

#define TT 1024
#define HH 1024
#define FF 768
#define EE 32
#define MAXTILE 96   // sum_e ceil(n_e/64) <= 4096/64 + 32

typedef __bf16 bf16;
typedef __bf16 v4bf __attribute__((ext_vector_type(4)));
typedef __bf16 v8bf __attribute__((ext_vector_type(8)));
typedef float  v4f  __attribute__((ext_vector_type(4)));

static __device__ __forceinline__ v4f mfma16(v8bf a, v8bf b, v4f c) {
    return __builtin_amdgcn_mfma_f32_16x16x32_bf16(a, b, c, 0, 0, 0);
}

// ---------------------------------------------------------------- router
// 1 wave per token. fp64 dot so top-k selection matches the high-precision
// reference. Top-k on LOGITS (exp monotone); full-softmax denom cancels under
// renormalization, so only the 4 kept exps are computed.
__global__ __launch_bounds__(64) void router_k(
    const float* __restrict__ x, const float* __restrict__ gw,
    bf16* __restrict__ xbf, int* __restrict__ tk_id, float* __restrict__ tk_w)
{
    int t = blockIdx.x, lane = threadIdx.x;
    float4 xr[4];
    const float4* xrow = (const float4*)(x + (size_t)t * HH);
#pragma unroll
    for (int i = 0; i < 4; ++i) xr[i] = xrow[i * 64 + lane];
#pragma unroll
    for (int i = 0; i < 4; ++i) {
        v4bf b = { (bf16)xr[i].x, (bf16)xr[i].y, (bf16)xr[i].z, (bf16)xr[i].w };
        *(v4bf*)(xbf + (size_t)t * HH + (i * 64 + lane) * 4) = b;
    }

    double acc[EE];
#pragma unroll
    for (int e = 0; e < EE; ++e) {
        const float4* grow = (const float4*)(gw + (size_t)e * HH);
        double a = 0.0;
#pragma unroll
        for (int i = 0; i < 4; ++i) {
            float4 g = grow[i * 64 + lane];
            a += (double)xr[i].x * g.x + (double)xr[i].y * g.y
               + (double)xr[i].z * g.z + (double)xr[i].w * g.w;
        }
        acc[e] = a;
    }
#pragma unroll
    for (int m = 1; m < 64; m <<= 1) {
#pragma unroll
        for (int e = 0; e < EE; ++e) acc[e] += __shfl_xor(acc[e], m, 64);
    }
    if (lane == 0) {
        int ids[4]; double lv[4];
        for (int k = 0; k < 4; ++k) {
            int best = 0; double bv = -1.0e300;
            for (int e = 0; e < EE; ++e)
                if (acc[e] > bv) { bv = acc[e]; best = e; }
            ids[k] = best; lv[k] = bv; acc[best] = -2.0e300;
        }
        double w[4], s = 0.0;
        for (int k = 0; k < 4; ++k) { w[k] = exp(lv[k] - lv[0]); s += w[k]; }
        for (int k = 0; k < 4; ++k) {
            tk_id[t * 4 + k] = ids[k];
            tk_w[t * 4 + k] = (float)(w[k] / s);
        }
    }
}

// ---------------------------------------------------------------- scatter
// Single block: count -> scan -> compact (token*4+k, weight) + build the
// (expert, m-tile) work list consumed by both GEMMs.
__global__ __launch_bounds__(1024) void scatter_k(
    const int* __restrict__ tk_id, const float* __restrict__ tk_w,
    int* __restrict__ cnt, int* __restrict__ offs,
    int* __restrict__ list, float* __restrict__ wlist,
    int* __restrict__ tile_e, int* __restrict__ tile_m)
{
    __shared__ int c_s[EE], o_s[EE], cur_s[EE];
    int tid = threadIdx.x;
    if (tid < EE) { c_s[tid] = 0; cur_s[tid] = 0; }
    __syncthreads();
    int ids[4]; float w[4];
#pragma unroll
    for (int k = 0; k < 4; ++k) { ids[k] = tk_id[tid * 4 + k]; w[k] = tk_w[tid * 4 + k]; }
#pragma unroll
    for (int k = 0; k < 4; ++k) atomicAdd(&c_s[ids[k]], 1);
    __syncthreads();
    if (tid == 0) {
        int a = 0;
        for (int e = 0; e < EE; ++e) { o_s[e] = a; a += c_s[e]; }
        // work list: one entry per 64-row m-tile, experts in order
        int nt = 0;
        for (int e = 0; e < EE; ++e)
            for (int m = 0; m * 64 < c_s[e]; ++m) { tile_e[nt] = e; tile_m[nt] = m; ++nt; }
        for (int i = nt; i < MAXTILE; ++i) { tile_e[i] = -1; tile_m[i] = 0; }
    }
    __syncthreads();
#pragma unroll
    for (int k = 0; k < 4; ++k) {
        int e = ids[k];
        int pos = atomicAdd(&cur_s[e], 1);
        int idx = o_s[e] + pos;
        list[idx] = tid * 4 + k;
        wlist[idx] = w[k];
    }
    if (tid < EE) { cnt[tid] = c_s[tid]; offs[tid] = o_s[tid]; }
    if (tid >= 1024 - 64) {                 // pad tail so tile reads stay in-bounds
        list[4096 + (tid - 960)] = 0;
        wlist[4096 + (tid - 960)] = 0.f;
    }
}

// ---------------------------------------------------------------- gemm1 + silu
// 1D grid 96*12, XCD-chunked swizzle. One 64-token m-tile per block.
// Tile 64 tokens x (64 g + 64 u), K=1024 step 64.
__global__ __launch_bounds__(256) void gemm1_k(
    const bf16* __restrict__ xbf, const float* __restrict__ w1,
    const int* __restrict__ cnt, const int* __restrict__ offs,
    const int* __restrict__ list, const int* __restrict__ tile_e,
    const int* __restrict__ tile_m, bf16* __restrict__ act)
{
    // bijective XCD swizzle: same-expert tiles land on the same XCD's L2
    int id = blockIdx.x;                    // 0..1151
    int p = (id & 7) * 144 + (id >> 3);
    int fb = p / MAXTILE, tl = p % MAXTILE;
    int e = tile_e[tl];
    if (e < 0) return;
    int mt = tile_m[tl];
    int n = cnt[e];
    int base = offs[e];

    __shared__ bf16 As[64][72];
    __shared__ bf16 Bs[128][72];

    int tid = threadIdx.x;
    int wid = tid >> 6, lane = tid & 63;
    int wr = wid >> 1, wc = wid & 1;
    int lrow = lane & 15, lk = (lane >> 4) * 8;
    const float* w1e = w1 + (size_t)e * 1536 * HH;

    // hoist gather indices (constant over k)
    int r0 = tid >> 3, r1 = 32 + (tid >> 3), oct = tid & 7;
    int tk0 = list[base + mt * 64 + r0] >> 2;
    int tk1 = list[base + mt * 64 + r1] >> 2;

    v4f accg[2][2], accu[2][2];
#pragma unroll
    for (int m = 0; m < 2; ++m)
#pragma unroll
        for (int nf = 0; nf < 2; ++nf) { accg[m][nf] = (v4f)0.f; accu[m][nf] = (v4f)0.f; }

    for (int k0 = 0; k0 < HH; k0 += 64) {
        // stage A (gathered token rows, bf16 direct)
        *(v8bf*)&As[r0][oct * 8] = *(const v8bf*)(xbf + (size_t)tk0 * HH + k0 + oct * 8);
        *(v8bf*)&As[r1][oct * 8] = *(const v8bf*)(xbf + (size_t)tk1 * HH + k0 + oct * 8);
        // stage B (w1 fp32 -> bf16): rows 0..63 = g, 64..127 = u
#pragma unroll
        for (int it = 0; it < 8; ++it) {
            int r = it * 16 + (tid >> 4);
            int q = tid & 15;
            int grow = (r < 64) ? (fb * 64 + r) : (768 + fb * 64 + (r - 64));
            float4 v = *(const float4*)(w1e + (size_t)grow * HH + k0 + q * 4);
            bf16* dst = &Bs[r][q * 4];
            dst[0] = (bf16)v.x; dst[1] = (bf16)v.y;
            dst[2] = (bf16)v.z; dst[3] = (bf16)v.w;
        }
        __syncthreads();
#pragma unroll
        for (int ks = 0; ks < 2; ++ks) {
            int kk = ks * 32 + lk;
            v8bf a0  = *(const v8bf*)&As[wr * 32 + lrow][kk];
            v8bf a1  = *(const v8bf*)&As[wr * 32 + 16 + lrow][kk];
            v8bf bg0 = *(const v8bf*)&Bs[wc * 32 + lrow][kk];
            v8bf bg1 = *(const v8bf*)&Bs[wc * 32 + 16 + lrow][kk];
            v8bf bu0 = *(const v8bf*)&Bs[64 + wc * 32 + lrow][kk];
            v8bf bu1 = *(const v8bf*)&Bs[64 + wc * 32 + 16 + lrow][kk];
            accg[0][0] = mfma16(a0, bg0, accg[0][0]);
            accg[0][1] = mfma16(a0, bg1, accg[0][1]);
            accg[1][0] = mfma16(a1, bg0, accg[1][0]);
            accg[1][1] = mfma16(a1, bg1, accg[1][1]);
            accu[0][0] = mfma16(a0, bu0, accu[0][0]);
            accu[0][1] = mfma16(a0, bu1, accu[0][1]);
            accu[1][0] = mfma16(a1, bu0, accu[1][0]);
            accu[1][1] = mfma16(a1, bu1, accu[1][1]);
        }
        __syncthreads();
    }
    // epilogue: act = silu(g) * u, masked store, compact layout
    int rb = wr * 32 + (lane >> 4) * 4;
#pragma unroll
    for (int m = 0; m < 2; ++m)
#pragma unroll
        for (int nf = 0; nf < 2; ++nf)
#pragma unroll
            for (int j = 0; j < 4; ++j) {
                int r = mt * 64 + rb + m * 16 + j;
                if (r < n) {
                    float g = accg[m][nf][j], u = accu[m][nf][j];
                    float a = g / (1.f + __expf(-g)) * u;
                    act[(size_t)(base + r) * FF + fb * 64 + wc * 32 + nf * 16 + lrow] = (bf16)a;
                }
            }
}

// ---------------------------------------------------------------- gemm2
// 1D grid 96*16, same swizzle. Tile 64 slots x 64 h, K=768 step 64.
// Scales rows by routing weight, writes per-slot fp32 rows (no atomics).
__global__ __launch_bounds__(256) void gemm2_k(
    const bf16* __restrict__ act, const float* __restrict__ w2,
    const int* __restrict__ cnt, const int* __restrict__ offs,
    const int* __restrict__ list, const float* __restrict__ wlist,
    const int* __restrict__ tile_e, const int* __restrict__ tile_m,
    float* __restrict__ ybuf)
{
    int id = blockIdx.x;                    // 0..1535
    int p = (id & 7) * 192 + (id >> 3);
    int hb = p / MAXTILE, tl = p % MAXTILE;
    int e = tile_e[tl];
    if (e < 0) return;
    int mt = tile_m[tl];
    int n = cnt[e];
    int base = offs[e];

    __shared__ bf16 As[64][72];
    __shared__ bf16 Bs[64][72];

    int tid = threadIdx.x;
    int wid = tid >> 6, lane = tid & 63;
    int wr = wid >> 1, wc = wid & 1;
    int lrow = lane & 15, lk = (lane >> 4) * 8;
    const float* w2e = w2 + (size_t)e * HH * FF;

    int r0 = tid >> 3, r1 = 32 + (tid >> 3), oct = tid & 7;
    const bf16* arow0 = act + (size_t)(base + mt * 64 + r0) * FF;
    const bf16* arow1 = act + (size_t)(base + mt * 64 + r1) * FF;

    v4f acc[2][2];
#pragma unroll
    for (int m = 0; m < 2; ++m)
#pragma unroll
        for (int nf = 0; nf < 2; ++nf) acc[m][nf] = (v4f)0.f;

    for (int k0 = 0; k0 < FF; k0 += 64) {
        *(v8bf*)&As[r0][oct * 8] = *(const v8bf*)(arow0 + k0 + oct * 8);
        *(v8bf*)&As[r1][oct * 8] = *(const v8bf*)(arow1 + k0 + oct * 8);
#pragma unroll
        for (int it = 0; it < 4; ++it) {
            int r = it * 16 + (tid >> 4);
            int q = tid & 15;
            float4 v = *(const float4*)(w2e + (size_t)(hb * 64 + r) * FF + k0 + q * 4);
            bf16* dst = &Bs[r][q * 4];
            dst[0] = (bf16)v.x; dst[1] = (bf16)v.y;
            dst[2] = (bf16)v.z; dst[3] = (bf16)v.w;
        }
        __syncthreads();
#pragma unroll
        for (int ks = 0; ks < 2; ++ks) {
            int kk = ks * 32 + lk;
            v8bf a0 = *(const v8bf*)&As[wr * 32 + lrow][kk];
            v8bf a1 = *(const v8bf*)&As[wr * 32 + 16 + lrow][kk];
            v8bf b0 = *(const v8bf*)&Bs[wc * 32 + lrow][kk];
            v8bf b1 = *(const v8bf*)&Bs[wc * 32 + 16 + lrow][kk];
            acc[0][0] = mfma16(a0, b0, acc[0][0]);
            acc[0][1] = mfma16(a0, b1, acc[0][1]);
            acc[1][0] = mfma16(a1, b0, acc[1][0]);
            acc[1][1] = mfma16(a1, b1, acc[1][1]);
        }
        __syncthreads();
    }
    int rb = wr * 32 + (lane >> 4) * 4;
#pragma unroll
    for (int m = 0; m < 2; ++m)
#pragma unroll
        for (int j = 0; j < 4; ++j) {
            int r = mt * 64 + rb + m * 16 + j;
            if (r < n) {
                int code = list[base + r];
                float w = wlist[base + r];
#pragma unroll
                for (int nf = 0; nf < 2; ++nf) {
                    int col = wc * 32 + nf * 16 + lrow;
                    ybuf[(size_t)code * HH + hb * 64 + col] = acc[m][nf][j] * w;
                }
            }
        }
}

// ---------------------------------------------------------------- combine
__global__ __launch_bounds__(256) void combine_k(
    const float* __restrict__ ybuf, float* __restrict__ out)
{
    int idx = blockIdx.x * 256 + threadIdx.x;   // float4 index
    int t = idx >> 8, c = idx & 255;
    const float4* yb = (const float4*)ybuf;
    float4 a = yb[(size_t)(t * 4 + 0) * 256 + c];
    float4 b = yb[(size_t)(t * 4 + 1) * 256 + c];
    float4 d = yb[(size_t)(t * 4 + 2) * 256 + c];
    float4 e = yb[(size_t)(t * 4 + 3) * 256 + c];
    float4 s;
    s.x = a.x + b.x + d.x + e.x;
    s.y = a.y + b.y + d.y + e.y;
    s.z = a.z + b.z + d.z + e.z;
    s.w = a.w + b.w + d.w + e.w;
    ((float4*)out)[(size_t)t * 256 + c] = s;
}

// ---------------------------------------------------------------- launch
extern "C" void kernel_launch(void* const* d_in, const int* in_sizes, int n_in,
                              void* d_out, int out_size, void* d_ws, size_t ws_size,
                              hipStream_t stream)
{
    const float* x  = (const float*)d_in[0];
    const float* gw = (const float*)d_in[1];
    const float* w1 = (const float*)d_in[2];
    const float* w2 = (const float*)d_in[3];
    float* out = (float*)d_out;

    char* ws = (char*)d_ws;
    size_t off = 0;
    auto alloc = [&](size_t bytes) {
        void* p = ws + off;
        off = (off + bytes + 255) & ~(size_t)255;
        return p;
    };
    bf16*  xbf    = (bf16*) alloc((size_t)TT * HH * 2);
    int*   tk_id  = (int*)  alloc(4096 * 4);
    float* tk_w   = (float*)alloc(4096 * 4);
    int*   cnt    = (int*)  alloc(EE * 4);
    int*   offs   = (int*)  alloc(EE * 4);
    int*   list   = (int*)  alloc(4160 * 4);
    float* wlist  = (float*)alloc(4160 * 4);
    int*   tile_e = (int*)  alloc(MAXTILE * 4);
    int*   tile_m = (int*)  alloc(MAXTILE * 4);
    bf16*  act    = (bf16*) alloc((size_t)4160 * FF * 2);
    float* ybuf   = (float*)alloc((size_t)4096 * HH * 4);

    router_k<<<TT, 64, 0, stream>>>(x, gw, xbf, tk_id, tk_w);
    scatter_k<<<1, 1024, 0, stream>>>(tk_id, tk_w, cnt, offs, list, wlist, tile_e, tile_m);
    gemm1_k<<<MAXTILE * 12, 256, 0, stream>>>(xbf, w1, cnt, offs, list, tile_e, tile_m, act);
    gemm2_k<<<MAXTILE * 16, 256, 0, stream>>>(act, w2, cnt, offs, list, wlist, tile_e, tile_m, ybuf);
    combine_k<<<1024, 256, 0, stream>>>(ybuf, out);
}